// Round 1
// baseline (282.424 us; speedup 1.0000x reference)
//
#include <hip/hip_runtime.h>
#include <math.h>

// Problem constants (fixed by the reference)
constexpr int NN = 32768;   // nodes
constexpr int SS = 32768;   // subgraph-node entries
constexpr int CC = 1024;    // clusters (B*P)
constexpr int EE = 16384;   // coarsen edges
constexpr int DD = 64;      // hidden dim (= feat dim F)
constexpr int BB = 16;      // graphs
constexpr int PP = 64;      // patches per graph
constexpr int NC = 10;      // classes

// ---------------------------------------------------------------------------
// Kernel 1: input MLP  h = relu(relu(x@W1+b1)@W2+b2)   [N,64]
// One wave (64 lanes) per row; lane j owns output column j; row values
// broadcast via __shfl (v_readlane).
// ---------------------------------------------------------------------------
__global__ __launch_bounds__(256) void k_mlp_in(
    const float* __restrict__ x,
    const float* __restrict__ W1, const float* __restrict__ b1,
    const float* __restrict__ W2, const float* __restrict__ b2,
    float* __restrict__ h, int N)
{
    __shared__ float w1[64 * 64], w2[64 * 64], bb1[64], bb2[64];
    int tid = threadIdx.x;
    for (int i = tid; i < 64 * 64; i += 256) { w1[i] = W1[i]; w2[i] = W2[i]; }
    if (tid < 64) { bb1[tid] = b1[tid]; bb2[tid] = b2[tid]; }
    __syncthreads();
    int j = tid & 63;
    int wv = tid >> 6;
    int wgl = blockIdx.x * 4 + wv;
    int nw = gridDim.x * 4;
    for (int r = wgl; r < N; r += nw) {
        float xv = x[r * 64 + j];
        float a1 = bb1[j];
#pragma unroll
        for (int i = 0; i < 64; ++i) a1 = fmaf(__shfl(xv, i), w1[i * 64 + j], a1);
        float t = fmaxf(a1, 0.f);
        float a2 = bb2[j];
#pragma unroll
        for (int i = 0; i < 64; ++i) a2 = fmaf(__shfl(t, i), w2[i * 64 + j], a2);
        h[r * 64 + j] = fmaxf(a2, 0.f);
    }
}

// ---------------------------------------------------------------------------
// Degree accumulation and normalized edge weights
// ---------------------------------------------------------------------------
__global__ void k_deg(const int* __restrict__ row, const float* __restrict__ attr,
                      float* __restrict__ deg, int E)
{
    int e = blockIdx.x * 256 + threadIdx.x;
    if (e < E) atomicAdd(&deg[row[e]], attr[e]);
}

__global__ void k_ea(const int* __restrict__ row, const int* __restrict__ col,
                     const float* __restrict__ attr, const float* __restrict__ deg,
                     float* __restrict__ ea, int E)
{
    int e = blockIdx.x * 256 + threadIdx.x;
    if (e < E) {
        float dr = deg[row[e]], dc = deg[col[e]];
        float ir = dr > 0.f ? 1.f / sqrtf(dr) : 0.f;
        float ic = dc > 0.f ? 1.f / sqrtf(dc) : 0.f;
        ea[e] = ir * attr[e] * ic;
    }
}

// ---------------------------------------------------------------------------
// Segment offsets for the (sorted) subgraphs_batch: segoff[c] = lower_bound(b, c)
// ---------------------------------------------------------------------------
__global__ void k_segoff(const int* __restrict__ batch, int* __restrict__ segoff,
                         int S, int C)
{
    int c = blockIdx.x * 256 + threadIdx.x;
    if (c > C) return;
    int lo = 0, hi = S;
    while (lo < hi) { int mid = (lo + hi) >> 1; if (batch[mid] < c) lo = mid + 1; else hi = mid; }
    segoff[c] = lo;
}

// ---------------------------------------------------------------------------
// Per-entry Q/K/V:  v = h[mapper[s]];
//   Q = relu(v@Wp1+bp1)@Wp2+bp2,  K = v@WK+bK,  V = v@WV+bV
// Wave-per-row like k_mlp_in. Wp1/WK/WV in LDS (48KB), Wp2 from global (L1-hot).
// ---------------------------------------------------------------------------
__global__ __launch_bounds__(256) void k_qkv(
    const float* __restrict__ h, const int* __restrict__ mapper,
    const float* __restrict__ Wp1, const float* __restrict__ bp1,
    const float* __restrict__ Wp2, const float* __restrict__ bp2,
    const float* __restrict__ WK, const float* __restrict__ bK,
    const float* __restrict__ WV, const float* __restrict__ bV,
    float* __restrict__ Q, float* __restrict__ K, float* __restrict__ V, int S)
{
    __shared__ float wp1[4096], wk[4096], wvv[4096];
    __shared__ float bb[4][64];
    int tid = threadIdx.x;
    for (int i = tid; i < 4096; i += 256) { wp1[i] = Wp1[i]; wk[i] = WK[i]; wvv[i] = WV[i]; }
    if (tid < 64) { bb[0][tid] = bp1[tid]; bb[1][tid] = bp2[tid]; bb[2][tid] = bK[tid]; bb[3][tid] = bV[tid]; }
    __syncthreads();
    int j = tid & 63;
    int wv = tid >> 6;
    int wgl = blockIdx.x * 4 + wv;
    int nw = gridDim.x * 4;
    for (int s = wgl; s < S; s += nw) {
        int m = mapper[s];
        float xv = h[m * 64 + j];
        float a1 = bb[0][j], aK = bb[2][j], aV = bb[3][j];
#pragma unroll
        for (int i = 0; i < 64; ++i) {
            float sv = __shfl(xv, i);
            a1 = fmaf(sv, wp1[i * 64 + j], a1);
            aK = fmaf(sv, wk[i * 64 + j], aK);
            aV = fmaf(sv, wvv[i * 64 + j], aV);
        }
        float t = fmaxf(a1, 0.f);
        float a2 = bb[1][j];
#pragma unroll
        for (int i = 0; i < 64; ++i) a2 = fmaf(__shfl(t, i), Wp2[i * 64 + j], a2);
        Q[s * 64 + j] = a2;
        K[s * 64 + j] = aK;
        V[s * 64 + j] = aV;
    }
}

// ---------------------------------------------------------------------------
// Per-cluster reduction (segments are contiguous since batch is sorted):
//   Qs  = sum Q[s]      -> post-MLP -> Qk = relu(...)
//   Ksk = relu(sum K / max(L,1))
//   Krsum = sum relu(K);  Vsum = sum V;  Msb[c][i][j] = sum relu(K_i)*V_j
// Block = 256 threads = 4 waves. grp g owns Msb rows [16g,16g+16), col j.
// ---------------------------------------------------------------------------
__global__ __launch_bounds__(256) void k_cluster(
    const float* __restrict__ Q, const float* __restrict__ K, const float* __restrict__ V,
    const int* __restrict__ segoff,
    const float* __restrict__ Wpo1, const float* __restrict__ bpo1,
    const float* __restrict__ Wpo2, const float* __restrict__ bpo2,
    float* __restrict__ Msb, float* __restrict__ Qk, float* __restrict__ Ksk,
    float* __restrict__ Vsum, float* __restrict__ Krsum, float* __restrict__ Lf)
{
    __shared__ float w1[4096], w2[4096], bb1[64], bb2[64], klds[64];
    int tid = threadIdx.x;
    for (int i = tid; i < 4096; i += 256) { w1[i] = Wpo1[i]; w2[i] = Wpo2[i]; }
    if (tid < 64) { bb1[tid] = bpo1[tid]; bb2[tid] = bpo2[tid]; }
    int c = blockIdx.x;
    int s0 = segoff[c], s1 = segoff[c + 1];
    int j = tid & 63, grp = tid >> 6;
    float msb[16];
#pragma unroll
    for (int r = 0; r < 16; ++r) msb[r] = 0.f;
    float acc = 0.f;   // grp0: Qs, grp1: Ksum, grp2: sum relu(K), grp3: Vsum
    __syncthreads();
    for (int s = s0; s < s1; ++s) {
        if (tid < 64) klds[tid] = fmaxf(K[s * 64 + tid], 0.f);
        __syncthreads();
        float vj = V[s * 64 + j];
#pragma unroll
        for (int r = 0; r < 16; ++r) msb[r] = fmaf(klds[grp * 16 + r], vj, msb[r]);
        if (grp == 0)       acc += Q[s * 64 + j];
        else if (grp == 1)  acc += K[s * 64 + j];
        else if (grp == 2)  acc += klds[j];
        else                acc += vj;
        __syncthreads();
    }
#pragma unroll
    for (int r = 0; r < 16; ++r) Msb[c * 4096 + (grp * 16 + r) * 64 + j] = msb[r];
    int L = s1 - s0;
    float Lm = (float)(L > 0 ? L : 1);
    if (grp == 1)      Ksk[c * 64 + j] = fmaxf(acc / Lm, 0.f);
    else if (grp == 2) Krsum[c * 64 + j] = acc;
    else if (grp == 3) Vsum[c * 64 + j] = acc;
    if (tid == 0) Lf[c] = (float)L;
    if (grp == 0) {
        // post deepset MLP on Qs (acc holds Qs[c][j] across wave 0)
        float a1 = bb1[j];
#pragma unroll
        for (int i = 0; i < 64; ++i) a1 = fmaf(__shfl(acc, i), w1[i * 64 + j], a1);
        float t = fmaxf(a1, 0.f);
        float a2 = bb2[j];
#pragma unroll
        for (int i = 0; i < 64; ++i) a2 = fmaf(__shfl(t, i), w2[i * 64 + j], a2);
        Qk[c * 64 + j] = fmaxf(a2, 0.f);
    }
}

// ---------------------------------------------------------------------------
// Build CSR of edges by source row
// ---------------------------------------------------------------------------
__global__ void k_count(const int* __restrict__ row, int* __restrict__ rowcnt, int E)
{
    int e = blockIdx.x * 256 + threadIdx.x;
    if (e < E) atomicAdd(&rowcnt[row[e]], 1);
}

__global__ __launch_bounds__(1024) void k_scan(const int* __restrict__ rowcnt,
                                               int* __restrict__ rowptr,
                                               int* __restrict__ rowfill, int C)
{
    __shared__ int buf[1024];
    int tid = threadIdx.x;
    int v = rowcnt[tid];
    buf[tid] = v;
    __syncthreads();
    for (int off = 1; off < 1024; off <<= 1) {
        int t = (tid >= off) ? buf[tid - off] : 0;
        __syncthreads();
        buf[tid] += t;
        __syncthreads();
    }
    int incl = buf[tid];
    if (tid == 0) rowptr[0] = 0;
    rowptr[tid + 1] = incl;
    rowfill[tid] = incl - v;   // exclusive prefix
}

__global__ void k_fill(const int* __restrict__ row, int* __restrict__ rowfill,
                       int* __restrict__ eidx, int E)
{
    int e = blockIdx.x * 256 + threadIdx.x;
    if (e < E) {
        int pos = atomicAdd(&rowfill[row[e]], 1);
        eidx[pos] = e;
    }
}

// ---------------------------------------------------------------------------
// Edge kernel: block per SOURCE r. Stage Msb[r] (16KB) in LDS once; for each
// out-edge e=(r->c):
//   d1 = Qk[c].Ksk[r]; d2 = Qk[c].Krsum[r]
//   H[c][j]  += ea*(sa2*d1*Vsum[r][j] + sb2*sum_i Qk[c][i]*Msb[r][i][j])
//   den[c]   += ea*(sa2*L_r*d1 + sb2*d2)
// ---------------------------------------------------------------------------
__global__ __launch_bounds__(256) void k_edges(
    const float* __restrict__ Msb, const float* __restrict__ Qk,
    const float* __restrict__ Ksk, const float* __restrict__ Vsum,
    const float* __restrict__ Krsum, const float* __restrict__ Lf,
    const float* __restrict__ ea, const int* __restrict__ col,
    const int* __restrict__ rowptr, const int* __restrict__ eidx,
    const float* __restrict__ alpha_beta,
    float* __restrict__ H, float* __restrict__ den)
{
    __shared__ float msb[4096], kskl[64], vsl[64], krl[64];
    int r = blockIdx.x;
    int e0 = rowptr[r], e1 = rowptr[r + 1];
    if (e0 == e1) return;
    int tid = threadIdx.x;
    for (int i = tid; i < 4096; i += 256) msb[i] = Msb[r * 4096 + i];
    if (tid < 64)       kskl[tid] = Ksk[r * 64 + tid];
    else if (tid < 128) vsl[tid - 64] = Vsum[r * 64 + tid - 64];
    else if (tid < 192) krl[tid - 128] = Krsum[r * 64 + tid - 128];
    __syncthreads();
    float a0 = alpha_beta[0], a1 = alpha_beta[1];
    float sa2 = 1.f + expf(a1 - a0);   // 1/softmax0
    float sb2 = 1.f + expf(a0 - a1);   // 1/softmax1
    float Lr = Lf[r];
    int j = tid & 63, wv = tid >> 6;
    for (int idx = e0 + wv; idx < e1; idx += 4) {
        int e = eidx[idx];
        int c = col[e];
        float w = ea[e];
        float qv = Qk[c * 64 + j];
        float p1 = qv * kskl[j];
        float p2 = qv * krl[j];
#pragma unroll
        for (int o = 32; o > 0; o >>= 1) { p1 += __shfl_xor(p1, o); p2 += __shfl_xor(p2, o); }
        float wj = 0.f;
#pragma unroll
        for (int i = 0; i < 64; ++i) wj = fmaf(__shfl(qv, i), msb[i * 64 + j], wj);
        float hc = w * (sa2 * p1 * vsl[j] + sb2 * wj);
        atomicAdd(&H[c * 64 + j], hc);
        if (j == 0) atomicAdd(&den[c], w * (sa2 * Lr * p1 + sb2 * p2));
    }
}

// ---------------------------------------------------------------------------
// Final: out=H/(den+1e-6); g = mean over patches; logits = relu(g@Wc1+bc1)@Wc2+bc2
// Block per graph (16 blocks, 64 threads).
// ---------------------------------------------------------------------------
__global__ __launch_bounds__(64) void k_final(
    const float* __restrict__ H, const float* __restrict__ den,
    const float* __restrict__ Wc1, const float* __restrict__ bc1,
    const float* __restrict__ Wc2, const float* __restrict__ bc2,
    float* __restrict__ out)
{
    int bg = blockIdx.x;
    int j = threadIdx.x;
    float acc = 0.f;
    for (int p = 0; p < PP; ++p) {
        int c = bg * PP + p;
        acc += H[c * 64 + j] / (den[c] + 1e-6f);
    }
    float g = acc * (1.f / (float)PP);
    int m = j & 31;
    float a1 = bc1[m];
#pragma unroll
    for (int i = 0; i < 64; ++i) a1 = fmaf(__shfl(g, i), Wc1[i * 32 + m], a1);
    float c1 = fmaxf(a1, 0.f);
    int n = (j < NC) ? j : 0;
    float a2 = bc2[n];
#pragma unroll
    for (int i = 0; i < 32; ++i) a2 = fmaf(__shfl(c1, i), Wc2[i * NC + n], a2);
    if (j < NC) out[bg * NC + j] = a2;
}

// ---------------------------------------------------------------------------
extern "C" void kernel_launch(void* const* d_in, const int* in_sizes, int n_in,
                              void* d_out, int out_size, void* d_ws, size_t ws_size,
                              hipStream_t stream)
{
    const float* x      = (const float*)d_in[0];
    const int*   mapper = (const int*)d_in[1];
    const int*   batch  = (const int*)d_in[2];
    const int*   row    = (const int*)d_in[3];
    const int*   col    = (const int*)d_in[4];
    const float* attr   = (const float*)d_in[5];
    const float* W_in1  = (const float*)d_in[6];
    const float* b_in1  = (const float*)d_in[7];
    const float* W_in2  = (const float*)d_in[8];
    const float* b_in2  = (const float*)d_in[9];
    const float* W_pre1 = (const float*)d_in[10];
    const float* b_pre1 = (const float*)d_in[11];
    const float* W_pre2 = (const float*)d_in[12];
    const float* b_pre2 = (const float*)d_in[13];
    const float* W_post1= (const float*)d_in[14];
    const float* b_post1= (const float*)d_in[15];
    const float* W_post2= (const float*)d_in[16];
    const float* b_post2= (const float*)d_in[17];
    const float* W_K    = (const float*)d_in[18];
    const float* b_K    = (const float*)d_in[19];
    const float* W_V    = (const float*)d_in[20];
    const float* b_V    = (const float*)d_in[21];
    const float* alpha_beta = (const float*)d_in[22];
    const float* W_c1   = (const float*)d_in[23];
    const float* b_c1   = (const float*)d_in[24];
    const float* W_c2   = (const float*)d_in[25];
    const float* b_c2   = (const float*)d_in[26];

    float* ws = (float*)d_ws;
    float* h     = ws;                       // N*64
    float* Q     = h     + (size_t)NN * 64;  // S*64
    float* K     = Q     + (size_t)SS * 64;
    float* V     = K     + (size_t)SS * 64;
    float* Msb   = V     + (size_t)SS * 64;  // C*64*64
    float* Qk    = Msb   + (size_t)CC * 4096;
    float* Ksk   = Qk    + (size_t)CC * 64;
    float* Vsum  = Ksk   + (size_t)CC * 64;
    float* Krsum = Vsum  + (size_t)CC * 64;
    float* eaw   = Krsum + (size_t)CC * 64;  // E
    float* Lf    = eaw   + (size_t)EE;       // C
    // --- zeroed region (contiguous) ---
    float* H     = Lf    + (size_t)CC;       // C*64
    float* den   = H     + (size_t)CC * 64;  // C
    float* deg   = den   + (size_t)CC;       // C
    int*  rowcnt = (int*)(deg + (size_t)CC); // C
    // --- end zeroed region ---
    int*  segoff = rowcnt + CC;              // C+1
    int*  rowptr = segoff + (CC + 1);        // C+1
    int*  rowfill= rowptr + (CC + 1);        // C
    int*  eidx   = rowfill+ (CC + 1);        // E

    size_t zero_bytes = ((size_t)CC * 64 + CC + CC + CC) * sizeof(float);
    hipMemsetAsync(H, 0, zero_bytes, stream);

    k_mlp_in<<<1024, 256, 0, stream>>>(x, W_in1, b_in1, W_in2, b_in2, h, NN);
    k_deg<<<EE / 256, 256, 0, stream>>>(row, attr, deg, EE);
    k_ea<<<EE / 256, 256, 0, stream>>>(row, col, attr, deg, eaw, EE);
    k_segoff<<<(CC + 256) / 256, 256, 0, stream>>>(batch, segoff, SS, CC);
    k_qkv<<<1024, 256, 0, stream>>>(h, mapper, W_pre1, b_pre1, W_pre2, b_pre2,
                                    W_K, b_K, W_V, b_V, Q, K, V, SS);
    k_cluster<<<CC, 256, 0, stream>>>(Q, K, V, segoff, W_post1, b_post1,
                                      W_post2, b_post2, Msb, Qk, Ksk, Vsum, Krsum, Lf);
    k_count<<<EE / 256, 256, 0, stream>>>(row, rowcnt, EE);
    k_scan<<<1, 1024, 0, stream>>>(rowcnt, rowptr, rowfill, CC);
    k_fill<<<EE / 256, 256, 0, stream>>>(row, rowfill, eidx, EE);
    k_edges<<<CC, 256, 0, stream>>>(Msb, Qk, Ksk, Vsum, Krsum, Lf, eaw, col,
                                    rowptr, eidx, alpha_beta, H, den);
    k_final<<<BB, 64, 0, stream>>>(H, den, W_c1, b_c1, W_c2, b_c2, (float*)d_out);
}

// Round 2
// 131.270 us; speedup vs baseline: 2.1515x; 2.1515x over previous
//
#include <hip/hip_runtime.h>
#include <math.h>

constexpr int NN = 32768;   // nodes
constexpr int SS = 32768;   // subgraph-node entries
constexpr int CC = 1024;    // clusters
constexpr int EE = 16384;   // coarsen edges
constexpr int BB = 16;      // graphs
constexpr int PP = 64;      // patches per graph
constexpr int NC = 10;      // classes

__device__ __forceinline__ float rdlane(float v, int l) {
    return __int_as_float(__builtin_amdgcn_readlane(__float_as_int(v), l));
}

// ---------------------------------------------------------------------------
// Fused per-node dense chain:
//   t1 = relu(x@W1+b1); h = relu(t1@W2+b2);
//   u  = relu(h@Wp1+bp1); Qpre = u@Wp2+bp2; K = h@WK+bK; V = h@WV+bV
// Block: 256 threads = 16x16, each computes 4 rows x 4 cols of a 64x64 tile.
// LDS tiles stored transposed [k][row] with stride 68 (16B aligned).
// ---------------------------------------------------------------------------
#define TSTRIDE 68

__device__ __forceinline__ void gemm64(const float* bIn, const float* w,
                                       const float* __restrict__ bias,
                                       int r0, int c0, float acc[4][4])
{
#pragma unroll
    for (int dc = 0; dc < 4; ++dc) {
        float bv = bias[c0 + dc];
        acc[0][dc] = bv; acc[1][dc] = bv; acc[2][dc] = bv; acc[3][dc] = bv;
    }
#pragma unroll 16
    for (int k = 0; k < 64; ++k) {
        float4 av = *(const float4*)(bIn + k * TSTRIDE + r0);
        float4 wv = *(const float4*)(w + k * TSTRIDE + c0);
        acc[0][0] = fmaf(av.x, wv.x, acc[0][0]); acc[0][1] = fmaf(av.x, wv.y, acc[0][1]);
        acc[0][2] = fmaf(av.x, wv.z, acc[0][2]); acc[0][3] = fmaf(av.x, wv.w, acc[0][3]);
        acc[1][0] = fmaf(av.y, wv.x, acc[1][0]); acc[1][1] = fmaf(av.y, wv.y, acc[1][1]);
        acc[1][2] = fmaf(av.y, wv.z, acc[1][2]); acc[1][3] = fmaf(av.y, wv.w, acc[1][3]);
        acc[2][0] = fmaf(av.z, wv.x, acc[2][0]); acc[2][1] = fmaf(av.z, wv.y, acc[2][1]);
        acc[2][2] = fmaf(av.z, wv.z, acc[2][2]); acc[2][3] = fmaf(av.z, wv.w, acc[2][3]);
        acc[3][0] = fmaf(av.w, wv.x, acc[3][0]); acc[3][1] = fmaf(av.w, wv.y, acc[3][1]);
        acc[3][2] = fmaf(av.w, wv.z, acc[3][2]); acc[3][3] = fmaf(av.w, wv.w, acc[3][3]);
    }
}

__device__ __forceinline__ void stageW(float* dst, const float* __restrict__ src, int tid)
{
#pragma unroll
    for (int t = 0; t < 16; ++t) {
        int idx = tid + t * 256;
        dst[(idx >> 6) * TSTRIDE + (idx & 63)] = src[idx];
    }
}

__device__ __forceinline__ void outT_relu(float* dst, int r0, int c0, float acc[4][4])
{
#pragma unroll
    for (int dc = 0; dc < 4; ++dc) {
        *(float4*)(dst + (c0 + dc) * TSTRIDE + r0) =
            make_float4(fmaxf(acc[0][dc], 0.f), fmaxf(acc[1][dc], 0.f),
                        fmaxf(acc[2][dc], 0.f), fmaxf(acc[3][dc], 0.f));
    }
}

__device__ __forceinline__ void outG(float* __restrict__ dst, size_t rowbase,
                                     int r0, int c0, float acc[4][4])
{
#pragma unroll
    for (int dr = 0; dr < 4; ++dr)
        *(float4*)(dst + (rowbase + r0 + dr) * 64 + c0) =
            make_float4(acc[dr][0], acc[dr][1], acc[dr][2], acc[dr][3]);
}

__global__ __launch_bounds__(256) void k_node(
    const float* __restrict__ x,
    const float* __restrict__ W1, const float* __restrict__ b1,
    const float* __restrict__ W2, const float* __restrict__ b2,
    const float* __restrict__ Wp1, const float* __restrict__ bp1,
    const float* __restrict__ Wp2, const float* __restrict__ bp2,
    const float* __restrict__ WK, const float* __restrict__ bK,
    const float* __restrict__ WV, const float* __restrict__ bV,
    float* __restrict__ Qpre, float* __restrict__ Kf, float* __restrict__ Vf)
{
    __shared__ __align__(16) float bufA[64 * TSTRIDE];
    __shared__ __align__(16) float bufB[64 * TSTRIDE];
    __shared__ __align__(16) float wlds[64 * TSTRIDE];
    int tid = threadIdx.x;
    int tx = tid & 15, ty = tid >> 4;
    int r0 = ty * 4, c0 = tx * 4;
    size_t rowbase = (size_t)blockIdx.x * 64;
    const float* xb = x + rowbase * 64;
    // stage x transposed into bufA
#pragma unroll
    for (int t = 0; t < 16; ++t) {
        int idx = tid + t * 256;
        bufA[(idx & 63) * TSTRIDE + (idx >> 6)] = xb[idx];
    }
    stageW(wlds, W1, tid);
    __syncthreads();
    float acc[4][4];
    // phase 0: t1 = relu(x@W1+b1) -> bufB
    gemm64(bufA, wlds, b1, r0, c0, acc);
    outT_relu(bufB, r0, c0, acc);
    __syncthreads();
    stageW(wlds, W2, tid);
    __syncthreads();
    // phase 1: h = relu(t1@W2+b2) -> bufA
    gemm64(bufB, wlds, b2, r0, c0, acc);
    outT_relu(bufA, r0, c0, acc);
    __syncthreads();
    stageW(wlds, Wp1, tid);
    __syncthreads();
    // phase 2: u = relu(h@Wp1+bp1) -> bufB
    gemm64(bufA, wlds, bp1, r0, c0, acc);
    outT_relu(bufB, r0, c0, acc);
    __syncthreads();
    stageW(wlds, Wp2, tid);
    __syncthreads();
    // phase 3: Qpre = u@Wp2+bp2 -> global
    gemm64(bufB, wlds, bp2, r0, c0, acc);
    outG(Qpre, rowbase, r0, c0, acc);
    __syncthreads();
    stageW(wlds, WK, tid);
    __syncthreads();
    // phase 4: K = h@WK+bK -> global
    gemm64(bufA, wlds, bK, r0, c0, acc);
    outG(Kf, rowbase, r0, c0, acc);
    __syncthreads();
    stageW(wlds, WV, tid);
    __syncthreads();
    // phase 5: V = h@WV+bV -> global
    gemm64(bufA, wlds, bV, r0, c0, acc);
    outG(Vf, rowbase, r0, c0, acc);
}

// ---------------------------------------------------------------------------
// deg + rowcnt in one pass
// ---------------------------------------------------------------------------
__global__ void k_prep1(const int* __restrict__ row, const float* __restrict__ attr,
                        float* __restrict__ deg, int* __restrict__ rowcnt, int E)
{
    int e = blockIdx.x * 256 + threadIdx.x;
    if (e < E) {
        int r = row[e];
        atomicAdd(&deg[r], attr[e]);
        atomicAdd(&rowcnt[r], 1);
    }
}

// ---------------------------------------------------------------------------
// scan of rowcnt -> rowptr/rowfill, plus segoff binary searches
// ---------------------------------------------------------------------------
__global__ __launch_bounds__(1024) void k_scan(
    const int* __restrict__ rowcnt, int* __restrict__ rowptr, int* __restrict__ rowfill,
    const int* __restrict__ batch, int* __restrict__ segoff)
{
    __shared__ int buf[1024];
    int tid = threadIdx.x;
    int v = rowcnt[tid];
    buf[tid] = v;
    __syncthreads();
    for (int off = 1; off < 1024; off <<= 1) {
        int t = (tid >= off) ? buf[tid - off] : 0;
        __syncthreads();
        buf[tid] += t;
        __syncthreads();
    }
    int incl = buf[tid];
    if (tid == 0) rowptr[0] = 0;
    rowptr[tid + 1] = incl;
    rowfill[tid] = incl - v;
    int lo = 0, hi = SS;
    while (lo < hi) { int mid = (lo + hi) >> 1; if (batch[mid] < tid) lo = mid + 1; else hi = mid; }
    segoff[tid] = lo;
    if (tid == 0) segoff[CC] = SS;
}

// ---------------------------------------------------------------------------
// normalized edge weights + CSR fill
// ---------------------------------------------------------------------------
__global__ void k_prep2(const int* __restrict__ row, const int* __restrict__ col,
                        const float* __restrict__ attr, const float* __restrict__ deg,
                        float* __restrict__ eaw, int* __restrict__ rowfill,
                        int* __restrict__ eidx, int E)
{
    int e = blockIdx.x * 256 + threadIdx.x;
    if (e < E) {
        int r = row[e];
        float dr = deg[r], dc = deg[col[e]];
        float ir = dr > 0.f ? 1.f / sqrtf(dr) : 0.f;
        float ic = dc > 0.f ? 1.f / sqrtf(dc) : 0.f;
        eaw[e] = ir * attr[e] * ic;
        int pos = atomicAdd(&rowfill[r], 1);
        eidx[pos] = e;
    }
}

// ---------------------------------------------------------------------------
// Per-cluster reduction: one wave per cluster, Msb in 64 VGPRs.
// ---------------------------------------------------------------------------
__global__ __launch_bounds__(64) void k_cluster(
    const float* __restrict__ Qpre, const float* __restrict__ Kf, const float* __restrict__ Vf,
    const int* __restrict__ mapper, const int* __restrict__ segoff,
    const float* __restrict__ Wpo1, const float* __restrict__ bpo1,
    const float* __restrict__ Wpo2, const float* __restrict__ bpo2,
    float* __restrict__ Msb, float* __restrict__ Qk, float* __restrict__ Ksk,
    float* __restrict__ Vsum, float* __restrict__ Krsum, float* __restrict__ Lf)
{
    int c = blockIdx.x;
    int j = threadIdx.x;
    int s0 = segoff[c], s1 = segoff[c + 1];
    float msb[64];
#pragma unroll
    for (int i = 0; i < 64; ++i) msb[i] = 0.f;
    float qs = 0.f, ks = 0.f, krs = 0.f, vs = 0.f;
    if (s0 < s1) {
        int m = mapper[s0];
        float kj = Kf[(size_t)m * 64 + j];
        float vj = Vf[(size_t)m * 64 + j];
        float qj = Qpre[(size_t)m * 64 + j];
        for (int s = s0; s < s1; ++s) {
            float kjc = kj, vjc = vj, qjc = qj;
            if (s + 1 < s1) {
                int m2 = mapper[s + 1];
                kj = Kf[(size_t)m2 * 64 + j];
                vj = Vf[(size_t)m2 * 64 + j];
                qj = Qpre[(size_t)m2 * 64 + j];
            }
            float kr = fmaxf(kjc, 0.f);
            qs += qjc; ks += kjc; krs += kr; vs += vjc;
#pragma unroll
            for (int i = 0; i < 64; ++i)
                msb[i] = fmaf(rdlane(kr, i), vjc, msb[i]);
        }
    }
    int L = s1 - s0;
#pragma unroll
    for (int i = 0; i < 64; ++i) Msb[(size_t)c * 4096 + i * 64 + j] = msb[i];
    float Lm = (float)(L > 0 ? L : 1);
    Ksk[c * 64 + j] = fmaxf(ks / Lm, 0.f);
    Krsum[c * 64 + j] = krs;
    Vsum[c * 64 + j] = vs;
    if (j == 0) Lf[c] = (float)L;
    // post-deepset MLP on Qs; Qk = relu(...)
    float a1 = bpo1[j];
#pragma unroll
    for (int i = 0; i < 64; ++i) a1 = fmaf(rdlane(qs, i), Wpo1[i * 64 + j], a1);
    float t = fmaxf(a1, 0.f);
    float a2 = bpo2[j];
#pragma unroll
    for (int i = 0; i < 64; ++i) a2 = fmaf(rdlane(t, i), Wpo2[i * 64 + j], a2);
    Qk[c * 64 + j] = fmaxf(a2, 0.f);
}

// ---------------------------------------------------------------------------
// Edge kernel: one wave per source r; Msb[r] in 64 VGPRs; prefetch next Qk row.
// ---------------------------------------------------------------------------
__global__ __launch_bounds__(64) void k_edges(
    const float* __restrict__ Msb, const float* __restrict__ Qk,
    const float* __restrict__ Ksk, const float* __restrict__ Vsum,
    const float* __restrict__ Krsum, const float* __restrict__ Lf,
    const float* __restrict__ eaw, const int* __restrict__ col,
    const int* __restrict__ rowptr, const int* __restrict__ eidx,
    const float* __restrict__ ab,
    float* __restrict__ H, float* __restrict__ den)
{
    int r = blockIdx.x;
    int e0 = rowptr[r], e1 = rowptr[r + 1];
    if (e0 == e1) return;
    int j = threadIdx.x;
    float msb[64];
#pragma unroll
    for (int i = 0; i < 64; ++i) msb[i] = Msb[(size_t)r * 4096 + i * 64 + j];
    float kskj = Ksk[r * 64 + j];
    float krj  = Krsum[r * 64 + j];
    float vsj  = Vsum[r * 64 + j];
    float Lr   = Lf[r];
    float a0 = ab[0], a1 = ab[1];
    float sa2 = 1.f + expf(a1 - a0);
    float sb2 = 1.f + expf(a0 - a1);

    int e = eidx[e0];
    int c = col[e];
    float w = eaw[e];
    float qv = Qk[c * 64 + j];
    for (int idx = e0; idx < e1; ++idx) {
        int cc = c; float wc = w, qc = qv;
        if (idx + 1 < e1) {
            int e2 = eidx[idx + 1];
            c = col[e2];
            w = eaw[e2];
            qv = Qk[c * 64 + j];
        }
        float p1 = qc * kskj;
        float p2 = qc * krj;
#pragma unroll
        for (int o = 32; o > 0; o >>= 1) { p1 += __shfl_xor(p1, o); p2 += __shfl_xor(p2, o); }
        float wj = 0.f;
#pragma unroll
        for (int i = 0; i < 64; ++i) wj = fmaf(rdlane(qc, i), msb[i], wj);
        float hc = wc * (sa2 * p1 * vsj + sb2 * wj);
        atomicAdd(&H[cc * 64 + j], hc);
        if (j == 0) atomicAdd(&den[cc], wc * (sa2 * Lr * p1 + sb2 * p2));
    }
}

// ---------------------------------------------------------------------------
// Final readout
// ---------------------------------------------------------------------------
__global__ __launch_bounds__(64) void k_final(
    const float* __restrict__ H, const float* __restrict__ den,
    const float* __restrict__ Wc1, const float* __restrict__ bc1,
    const float* __restrict__ Wc2, const float* __restrict__ bc2,
    float* __restrict__ out)
{
    int bg = blockIdx.x;
    int j = threadIdx.x;
    float acc = 0.f;
    for (int p = 0; p < PP; ++p) {
        int c = bg * PP + p;
        acc += H[c * 64 + j] / (den[c] + 1e-6f);
    }
    float g = acc * (1.f / (float)PP);
    int m = j & 31;
    float a1 = bc1[m];
#pragma unroll
    for (int i = 0; i < 64; ++i) a1 = fmaf(rdlane(g, i), Wc1[i * 32 + m], a1);
    float c1 = fmaxf(a1, 0.f);
    int n = (j < NC) ? j : 0;
    float a2 = bc2[n];
#pragma unroll
    for (int i = 0; i < 32; ++i) a2 = fmaf(rdlane(c1, i), Wc2[i * NC + n], a2);
    if (j < NC) out[bg * NC + j] = a2;
}

// ---------------------------------------------------------------------------
extern "C" void kernel_launch(void* const* d_in, const int* in_sizes, int n_in,
                              void* d_out, int out_size, void* d_ws, size_t ws_size,
                              hipStream_t stream)
{
    const float* x      = (const float*)d_in[0];
    const int*   mapper = (const int*)d_in[1];
    const int*   batch  = (const int*)d_in[2];
    const int*   row    = (const int*)d_in[3];
    const int*   col    = (const int*)d_in[4];
    const float* attr   = (const float*)d_in[5];
    const float* W_in1  = (const float*)d_in[6];
    const float* b_in1  = (const float*)d_in[7];
    const float* W_in2  = (const float*)d_in[8];
    const float* b_in2  = (const float*)d_in[9];
    const float* W_pre1 = (const float*)d_in[10];
    const float* b_pre1 = (const float*)d_in[11];
    const float* W_pre2 = (const float*)d_in[12];
    const float* b_pre2 = (const float*)d_in[13];
    const float* W_post1= (const float*)d_in[14];
    const float* b_post1= (const float*)d_in[15];
    const float* W_post2= (const float*)d_in[16];
    const float* b_post2= (const float*)d_in[17];
    const float* W_K    = (const float*)d_in[18];
    const float* b_K    = (const float*)d_in[19];
    const float* W_V    = (const float*)d_in[20];
    const float* b_V    = (const float*)d_in[21];
    const float* alpha_beta = (const float*)d_in[22];
    const float* W_c1   = (const float*)d_in[23];
    const float* b_c1   = (const float*)d_in[24];
    const float* W_c2   = (const float*)d_in[25];
    const float* b_c2   = (const float*)d_in[26];

    float* ws = (float*)d_ws;
    float* Qpre  = ws;                        // N*64
    float* Kf    = Qpre  + (size_t)NN * 64;
    float* Vf    = Kf    + (size_t)NN * 64;
    float* Msb   = Vf    + (size_t)NN * 64;   // C*4096
    float* Qk    = Msb   + (size_t)CC * 4096;
    float* Ksk   = Qk    + (size_t)CC * 64;
    float* Vsum  = Ksk   + (size_t)CC * 64;
    float* Krsum = Vsum  + (size_t)CC * 64;
    float* eaw   = Krsum + (size_t)CC * 64;   // E
    float* Lf    = eaw   + (size_t)EE;        // C
    // --- zeroed region (contiguous) ---
    float* H     = Lf    + (size_t)CC;        // C*64
    float* den   = H     + (size_t)CC * 64;   // C
    float* deg   = den   + (size_t)CC;        // C
    int*  rowcnt = (int*)(deg + (size_t)CC);  // C
    // --- end zeroed region ---
    int*  segoff = rowcnt + CC;               // C+1
    int*  rowptr = segoff + (CC + 1);         // C+1
    int*  rowfill= rowptr + (CC + 1);         // C
    int*  eidx   = rowfill+ (CC + 1);         // E

    size_t zero_bytes = ((size_t)CC * 64 + CC + CC + CC) * sizeof(float);
    hipMemsetAsync(H, 0, zero_bytes, stream);

    k_prep1<<<EE / 256, 256, 0, stream>>>(row, attr, deg, rowcnt, EE);
    k_scan<<<1, 1024, 0, stream>>>(rowcnt, rowptr, rowfill, batch, segoff);
    k_prep2<<<EE / 256, 256, 0, stream>>>(row, col, attr, deg, eaw, rowfill, eidx, EE);
    k_node<<<NN / 64, 256, 0, stream>>>(x, W_in1, b_in1, W_in2, b_in2,
                                        W_pre1, b_pre1, W_pre2, b_pre2,
                                        W_K, b_K, W_V, b_V, Qpre, Kf, Vf);
    k_cluster<<<CC, 64, 0, stream>>>(Qpre, Kf, Vf, mapper, segoff,
                                     W_post1, b_post1, W_post2, b_post2,
                                     Msb, Qk, Ksk, Vsum, Krsum, Lf);
    k_edges<<<CC, 64, 0, stream>>>(Msb, Qk, Ksk, Vsum, Krsum, Lf, eaw, col,
                                   rowptr, eidx, alpha_beta, H, den);
    k_final<<<BB, 64, 0, stream>>>(H, den, W_c1, b_c1, W_c2, b_c2, (float*)d_out);
}